// Round 9
// baseline (131.094 us; speedup 1.0000x reference)
//
#include <hip/hip_runtime.h>

#define IMG    512
#define TW     32
#define TH     16
#define R      5
#define KW     11
#define HB_H   (TH + 2*R)            // 26
#define W4     33                    // hb4 padded row stride (float4 cells)
#define W1     37                    // hb1 padded row stride (floats; odd)
#define GX     (IMG / TW)            // 16
#define GY     (IMG / TH)            // 32
#define NBATCH 32
#define NBLOCKS (GX * GY * NBATCH)   // 16384
#define NSLOTS  64
#define PERSLOT (NBLOCKS / NSLOTS)   // 256
#define C1f 0.0001f
#define C2f 0.0009f

#define SCALEF    16777216.0f        // 2^24
#define SSHIFT    45
#define BIAS1     (1ll << 36)
#define GSHIFT    50
#define BIAS2     (1ll << 43)

typedef float v2f __attribute__((ext_vector_type(2)));

// LDS = 26*33*16 + 26*37*4 + 16 = 17,592 B -> 8 blocks/CU when VGPR<=64.
// VALU-issue-bound (R8: occupancy 2x -> dur flat, VALUBusy 79%). This round:
// j-outer/k-inner conv (share xx/yy/xy products; deny the compiler's VGPR-32
// rematerialization) + 2-wide packed fp32 (v_pk_fma_f32) for (mu_x,mu_y) and
// (xx,yy) lanes: 5 FMA/tap -> 2 pk_fma + 1 fma.
__global__ __launch_bounds__(256, 4) void ssim_fused_kernel(
    const float* __restrict__ x, const float* __restrict__ y,
    float* __restrict__ out, unsigned long long* __restrict__ ws)
{
    __shared__ float4 hb4[HB_H][W4];  // (mu_x, mu_y, E[xx], E[yy]) horiz-filtered
    __shared__ float  hb1[HB_H][W1];  // E[xy] horiz-filtered
    __shared__ float  red[4];

    // normalized 1D Gaussian, sigma=1.5, k=11
    const float W[KW] = {
        0.00102838f, 0.00759874f, 0.03600077f, 0.10936075f, 0.21300553f,
        0.26601172f,
        0.21300553f, 0.10936075f, 0.03600077f, 0.00759874f, 0.00102838f};

    const int tc = blockIdx.x, tr = blockIdx.y, b = blockIdx.z;
    const int tid = threadIdx.x;
    const size_t imgBase = (size_t)b * (IMG * IMG);
    const int gr0 = tr * TH - R;
    const bool colEdge = (tc == 0) || (tc == GX - 1);

    // ========== horizontal pass: 4-px items, single trip (208 <= 256) ==========
    if (tid < HB_H * 8) {
        const int rr = tid >> 3;         // staged row 0..25
        const int g  = tid & 7;          // 4-px group in row
        const int gr = gr0 + rr;
        const bool rowok = (unsigned)gr < (unsigned)IMG;
        if (rowok) {
            const float4* rx = (const float4*)(x + imgBase + (size_t)gr * IMG);
            const float4* ry = (const float4*)(y + imgBase + (size_t)gr * IMG);
            const int c4 = tc * 8 + g - 2;   // first float4; taps use floats f[3..16]
            float fx[20], fy[20];
            if (colEdge) {
#pragma unroll
                for (int i = 0; i < 5; ++i) {
                    int q = c4 + i;
                    int qc = min(max(q, 0), IMG / 4 - 1);
                    float4 vx = rx[qc], vy = ry[qc];
                    float m = (q == qc) ? 1.f : 0.f;
                    fx[4*i+0]=vx.x*m; fx[4*i+1]=vx.y*m; fx[4*i+2]=vx.z*m; fx[4*i+3]=vx.w*m;
                    fy[4*i+0]=vy.x*m; fy[4*i+1]=vy.y*m; fy[4*i+2]=vy.z*m; fy[4*i+3]=vy.w*m;
                }
            } else {
#pragma unroll
                for (int i = 0; i < 5; ++i) {
                    float4 vx = rx[c4 + i], vy = ry[c4 + i];
                    fx[4*i+0]=vx.x; fx[4*i+1]=vx.y; fx[4*i+2]=vx.z; fx[4*i+3]=vx.w;
                    fy[4*i+0]=vy.x; fy[4*i+1]=vy.y; fy[4*i+2]=vy.z; fy[4*i+3]=vy.w;
                }
            }
            // j-outer / k-inner: each input's products computed ONCE,
            // FMA'd into <=4 output accumulators. Packed 2-wide fp32.
            v2f m[4], s[4];                  // (mu_x,mu_y), (xx,yy)
            float c[4];                      // xy
#pragma unroll
            for (int k = 0; k < 4; ++k) { m[k] = (v2f)(0.f); s[k] = (v2f)(0.f); c[k] = 0.f; }
#pragma unroll
            for (int j = 0; j < 14; ++j) {   // input f[3+j], j=0..13
                const v2f p  = { fx[3 + j], fy[3 + j] };
                const v2f pp = p * p;        // v_pk_mul_f32
                const float pq = fx[3 + j] * fy[3 + j];
#pragma unroll
                for (int k = 0; k < 4; ++k) {
                    const int u = j - k;
                    if (u >= 0 && u < KW) {  // constant-folds under full unroll
                        const float wt = W[u];
                        m[k] += wt * p;      // v_pk_fma_f32
                        s[k] += wt * pp;     // v_pk_fma_f32
                        c[k] += wt * pq;     // v_fma_f32
                    }
                }
            }
#pragma unroll
            for (int k = 0; k < 4; ++k) {
                hb4[rr][4*g + k] = make_float4(m[k].x, m[k].y, s[k].x, s[k].y);
                hb1[rr][4*g + k] = c[k];
            }
        } else {
            const float4 z = make_float4(0.f, 0.f, 0.f, 0.f);
#pragma unroll
            for (int k = 0; k < 4; ++k) {
                hb4[rr][4*g + k] = z;
                hb1[rr][4*g + k] = 0.f;
            }
        }
    }
    __syncthreads();

    // ========== vertical pass + SSIM epilogue: 2 rows/thread ==========
    const int tx = tid & 31;
    const int ty = tid >> 5;
    const int r0 = ty * 2;

    v2f vm[2], vs[2];
    float vc[2];
#pragma unroll
    for (int k = 0; k < 2; ++k) { vm[k] = (v2f)(0.f); vs[k] = (v2f)(0.f); vc[k] = 0.f; }

#pragma unroll
    for (int t = 0; t < 12; ++t) {       // tap rows r0 .. r0+11
        const float4 v4 = hb4[r0 + t][tx];
        const float  v1 = hb1[r0 + t][tx];
        const v2f a = { v4.x, v4.y };    // (mu_x, mu_y)
        const v2f d = { v4.z, v4.w };    // (xx, yy)
#pragma unroll
        for (int k = 0; k < 2; ++k) {
            const int u = t - k;
            if (u >= 0 && u < KW) {
                const float wt = W[u];
                vm[k] += wt * a;         // v_pk_fma_f32
                vs[k] += wt * d;         // v_pk_fma_f32
                vc[k] += wt * v1;        // v_fma_f32
            }
        }
    }

    float lsum = 0.f;
#pragma unroll
    for (int k = 0; k < 2; ++k) {
        const float mux = vm[k].x, muy = vm[k].y;
        const float sxx = vs[k].x - mux * mux;
        const float syy = vs[k].y - muy * muy;
        const float sxy = vc[k]   - mux * muy;
        const float num = (2.f * mux * muy + C1f) * (2.f * sxy + C2f);
        const float den = (mux * mux + muy * muy + C1f) * (sxx + syy + C2f);
        float ssim = num / (den + 1e-12f);
        ssim = fminf(fmaxf(ssim, -1.f + 1e-6f), 1.f - 1e-6f);
        lsum += ssim;
    }

    // ========== block reduction + fence-free packed-atomic finalize ==========
#pragma unroll
    for (int off = 32; off > 0; off >>= 1)
        lsum += __shfl_down(lsum, off, 64);
    if ((tid & 63) == 0) red[tid >> 6] = lsum;
    __syncthreads();
    if (tid == 0) {
        const float s = red[0] + red[1] + red[2] + red[3];
        const int fid  = ((b * GY) + tr) * GX + tc;
        const int slot = fid & (NSLOTS - 1);

        const long long v = (long long)llrintf(s * SCALEF);   // |v| <= 2^33
        const unsigned long long sAdd =
            (1ull << SSHIFT) | (unsigned long long)(v + BIAS1);
        unsigned long long old = atomicAdd(&ws[16 * slot], sAdd);
        if ((old >> SSHIFT) == (unsigned long long)(PERSLOT - 1)) {
            const long long slotSum =
                (long long)((old & ((1ull << SSHIFT) - 1)) +
                            (unsigned long long)(v + BIAS1))
                - (long long)PERSLOT * BIAS1;
            const unsigned long long gAdd =
                (1ull << GSHIFT) | (unsigned long long)(slotSum + BIAS2);
            unsigned long long gold = atomicAdd(&ws[16 * NSLOTS], gAdd);
            if ((gold >> GSHIFT) == (unsigned long long)(NSLOTS - 1)) {
                const long long total =
                    (long long)((gold & ((1ull << GSHIFT) - 1)) +
                                (unsigned long long)(slotSum + BIAS2))
                    - (long long)NSLOTS * BIAS2;
                const double mean =
                    (double)total / ((double)SCALEF * (double)NBLOCKS * (double)(TW * TH));
                out[0] = (float)(1.0 - mean);
            }
        }
    }
}

extern "C" void kernel_launch(void* const* d_in, const int* in_sizes, int n_in,
                              void* d_out, int out_size, void* d_ws, size_t ws_size,
                              hipStream_t stream) {
    const float* x = (const float*)d_in[0];
    const float* y = (const float*)d_in[1];
    float* out = (float*)d_out;
    unsigned long long* ws = (unsigned long long*)d_ws;

    hipMemsetAsync(d_ws, 0, (NSLOTS + 1) * 128, stream);
    dim3 grid(GX, GY, NBATCH);
    ssim_fused_kernel<<<grid, 256, 0, stream>>>(x, y, out, ws);
}

// Round 10
// 118.125 us; speedup vs baseline: 1.1098x; 1.1098x over previous
//
#include <hip/hip_runtime.h>

#define IMG    512
#define TW     32
#define TH     64
#define R      5
#define KW     11
#define HB_H   (TH + 2*R)            // 74
#define W4     33                    // hb4 padded row stride (float4 cells)
#define GX     (IMG / TW)            // 16
#define GY     (IMG / TH)            // 8
#define NBATCH 32
#define NBLOCKS (GX * GY * NBATCH)   // 4096
#define NSLOTS  64
#define PERSLOT (NBLOCKS / NSLOTS)   // 64
#define C1f 0.0001f
#define C2f 0.0009f

#define SCALEF    16777216.0f        // 2^24 ; |v| <= 2048*2^24 = 2^35
#define SSHIFT    45
#define BIAS1     (1ll << 36)
#define GSHIFT    50
#define BIAS2     (1ll << 43)

typedef float v2f __attribute__((ext_vector_type(2)));

// u=x+y, v=x-y basis: only 4 conv channels (mu_u, mu_v, E[u2], E[v2]) = 2 pk
// accumulators. LDS: single float4 plane 74*33*16 = 39,072 B -> 4 blocks/CU.
// pos permutation pos(c) = (c>>3) | ((c&7)<<2) used by writer AND reader:
// same-rr writers (g=0..3) land in distinct bank groups (conflict-free).
__global__ __launch_bounds__(256, 4) void ssim_fused_kernel(
    const float* __restrict__ x, const float* __restrict__ y,
    float* __restrict__ out, unsigned long long* __restrict__ ws)
{
    __shared__ float4 hb4[HB_H][W4];  // (mu_u, mu_v, Su, Sv) horiz-filtered
    __shared__ float  red[4];

    // normalized 1D Gaussian, sigma=1.5, k=11
    const float W[KW] = {
        0.00102838f, 0.00759874f, 0.03600077f, 0.10936075f, 0.21300553f,
        0.26601172f,
        0.21300553f, 0.10936075f, 0.03600077f, 0.00759874f, 0.00102838f};

    const int tc = blockIdx.x, tr = blockIdx.y, b = blockIdx.z;
    const int tid = threadIdx.x;
    const size_t imgBase = (size_t)b * (IMG * IMG);
    const int gr0 = tr * TH - R;
    const bool colEdge = (tc == 0) || (tc == GX - 1);

    // ========== horizontal pass: 8-px items, 296 items (1 ragged wave) ======
    for (int i = tid; i < HB_H * 4; i += 256) {
        const int rr = i >> 2;           // staged row 0..73
        const int g  = i & 3;            // 8-px group in row
        const int gr = gr0 + rr;
        if ((unsigned)gr < (unsigned)IMG) {
            const float4* rx = (const float4*)(x + imgBase + (size_t)gr * IMG);
            const float4* ry = (const float4*)(y + imgBase + (size_t)gr * IMG);
            const int q0 = tc * 8 + 2 * g - 2;  // 6 float4 = f[0..23]; taps f[3..20]
            float fx[24], fy[24];
            if (colEdge) {
#pragma unroll
                for (int i4 = 0; i4 < 6; ++i4) {
                    int q = q0 + i4;
                    int qc = min(max(q, 0), IMG / 4 - 1);
                    float4 vx = rx[qc], vy = ry[qc];
                    float m = (q == qc) ? 1.f : 0.f;
                    fx[4*i4+0]=vx.x*m; fx[4*i4+1]=vx.y*m; fx[4*i4+2]=vx.z*m; fx[4*i4+3]=vx.w*m;
                    fy[4*i4+0]=vy.x*m; fy[4*i4+1]=vy.y*m; fy[4*i4+2]=vy.z*m; fy[4*i4+3]=vy.w*m;
                }
            } else {
#pragma unroll
                for (int i4 = 0; i4 < 6; ++i4) {
                    float4 vx = rx[q0 + i4], vy = ry[q0 + i4];
                    fx[4*i4+0]=vx.x; fx[4*i4+1]=vx.y; fx[4*i4+2]=vx.z; fx[4*i4+3]=vx.w;
                    fy[4*i4+0]=vy.x; fy[4*i4+1]=vy.y; fy[4*i4+2]=vy.z; fy[4*i4+3]=vy.w;
                }
            }
            // j-outer / k-inner, u/v basis, all-pk accumulation
            v2f m[8], s[8];
#pragma unroll
            for (int k = 0; k < 8; ++k) { m[k] = (v2f)(0.f); s[k] = (v2f)(0.f); }
#pragma unroll
            for (int j = 0; j < 18; ++j) {        // input f[3+j]
                const float a = fx[3 + j], c = fy[3 + j];
                const v2f p  = { a + c, a - c };  // (u, v)
                const v2f pp = p * p;             // (u2, v2) pk_mul
#pragma unroll
                for (int k = 0; k < 8; ++k) {
                    const int t = j - k;
                    if (t >= 0 && t < KW) {       // constant-folds
                        const float wt = W[t];
                        m[k] += wt * p;           // pk_fma
                        s[k] += wt * pp;          // pk_fma
                    }
                }
            }
#pragma unroll
            for (int k = 0; k < 8; ++k) {
                const int pos = g + 4 * k;        // permuted column slot
                hb4[rr][pos] = make_float4(m[k].x, m[k].y, s[k].x, s[k].y);
            }
        } else {
            const float4 z = make_float4(0.f, 0.f, 0.f, 0.f);
#pragma unroll
            for (int k = 0; k < 8; ++k) hb4[rr][g + 4 * k] = z;
        }
    }
    __syncthreads();

    // ========== vertical pass + SSIM epilogue: 8 rows/thread ==========
    const int tx  = tid & 31;
    const int ty  = tid >> 5;
    const int r0  = ty * 8;
    const int pos = (tx >> 3) + ((tx & 7) << 2); // same permutation as writer

    v2f vm[8], vs[8];
#pragma unroll
    for (int k = 0; k < 8; ++k) { vm[k] = (v2f)(0.f); vs[k] = (v2f)(0.f); }

#pragma unroll
    for (int t = 0; t < 18; ++t) {       // staged rows r0 .. r0+17
        const float4 h = hb4[r0 + t][pos];
        const v2f a = { h.x, h.y };      // (mu_u, mu_v)
        const v2f d = { h.z, h.w };      // (Su, Sv)
#pragma unroll
        for (int k = 0; k < 8; ++k) {
            const int u = t - k;
            if (u >= 0 && u < KW) {
                const float wt = W[u];
                vm[k] += wt * a;         // pk_fma
                vs[k] += wt * d;         // pk_fma
            }
        }
    }

    float lsum = 0.f;
#pragma unroll
    for (int k = 0; k < 8; ++k) {
        const v2f sq = vm[k] * vm[k];    // (A, B) = (mu_u^2, mu_v^2)
        const float A = sq.x, B = sq.y;
        const float Su = vs[k].x, Sv = vs[k].y;
        const float AmB = A - B, ApB = A + B;
        const float t1 = 0.5f * AmB + C1f;                 // 2 mux muy + C1
        const float t2 = 0.5f * ((Su - Sv) - AmB) + C2f;   // 2 sxy + C2
        const float t3 = 0.5f * ApB + C1f;                 // mux^2+muy^2 + C1
        const float t4 = 0.5f * ((Su + Sv) - ApB) + C2f;   // sx+sy + C2
        float ssim = (t1 * t2) / (t3 * t4 + 1e-12f);
        ssim = fminf(fmaxf(ssim, -1.f + 1e-6f), 1.f - 1e-6f);
        lsum += ssim;
    }

    // ========== block reduction + fence-free packed-atomic finalize ==========
#pragma unroll
    for (int off = 32; off > 0; off >>= 1)
        lsum += __shfl_down(lsum, off, 64);
    if ((tid & 63) == 0) red[tid >> 6] = lsum;
    __syncthreads();
    if (tid == 0) {
        const float s = red[0] + red[1] + red[2] + red[3];
        const int fid  = ((b * GY) + tr) * GX + tc;
        const int slot = fid & (NSLOTS - 1);

        const long long v = (long long)llrintf(s * SCALEF);   // |v| <= 2^35
        const unsigned long long sAdd =
            (1ull << SSHIFT) | (unsigned long long)(v + BIAS1);
        unsigned long long old = atomicAdd(&ws[16 * slot], sAdd);
        if ((old >> SSHIFT) == (unsigned long long)(PERSLOT - 1)) {
            const long long slotSum =
                (long long)((old & ((1ull << SSHIFT) - 1)) +
                            (unsigned long long)(v + BIAS1))
                - (long long)PERSLOT * BIAS1;
            const unsigned long long gAdd =
                (1ull << GSHIFT) | (unsigned long long)(slotSum + BIAS2);
            unsigned long long gold = atomicAdd(&ws[16 * NSLOTS], gAdd);
            if ((gold >> GSHIFT) == (unsigned long long)(NSLOTS - 1)) {
                const long long total =
                    (long long)((gold & ((1ull << GSHIFT) - 1)) +
                                (unsigned long long)(slotSum + BIAS2))
                    - (long long)NSLOTS * BIAS2;
                const double mean =
                    (double)total / ((double)SCALEF * (double)NBLOCKS * (double)(TW * TH));
                out[0] = (float)(1.0 - mean);
            }
        }
    }
}

extern "C" void kernel_launch(void* const* d_in, const int* in_sizes, int n_in,
                              void* d_out, int out_size, void* d_ws, size_t ws_size,
                              hipStream_t stream) {
    const float* x = (const float*)d_in[0];
    const float* y = (const float*)d_in[1];
    float* out = (float*)d_out;
    unsigned long long* ws = (unsigned long long*)d_ws;

    hipMemsetAsync(d_ws, 0, (NSLOTS + 1) * 128, stream);
    dim3 grid(GX, GY, NBATCH);
    ssim_fused_kernel<<<grid, 256, 0, stream>>>(x, y, out, ws);
}

// Round 11
// 112.071 us; speedup vs baseline: 1.1697x; 1.0540x over previous
//
#include <hip/hip_runtime.h>

#define IMG    512
#define TW     32
#define TH     32
#define R      5
#define KW     11
#define HB_H   (TH + 2*R)            // 42
#define W4     33                    // hb4 padded row stride (float4 cells)
#define GX     (IMG / TW)            // 16
#define GY     (IMG / TH)            // 16
#define NBATCH 32
#define NBLOCKS (GX * GY * NBATCH)   // 8192
#define NSLOTS  64
#define PERSLOT (NBLOCKS / NSLOTS)   // 128
#define C1f 0.0001f
#define C2f 0.0009f

#define SCALEF    16777216.0f        // 2^24 ; |v| <= 1024*2^24 = 2^34
#define SSHIFT    45
#define BIAS1     (1ll << 36)
#define GSHIFT    50
#define BIAS2     (1ll << 43)

typedef float v2f __attribute__((ext_vector_type(2)));

// u=x+y, v=x-y basis: 4 conv channels (mu_u, mu_v, E[u2], E[v2]) = 2 pk accs.
// LDS: 42*33*16 + 16 = 22,192 B -> 7 blocks/CU (28 waves, 87%) if VGPR<=73.
// R10 was 39 KB -> 4 blocks, latency-bound at VALUBusy 46%. Permutation
// pos(c) = (c>>3) + ((c&7)<<2) shared by writer/reader: conflict-free.
__global__ __launch_bounds__(256, 4) void ssim_fused_kernel(
    const float* __restrict__ x, const float* __restrict__ y,
    float* __restrict__ out, unsigned long long* __restrict__ ws)
{
    __shared__ float4 hb4[HB_H][W4];  // (mu_u, mu_v, Su, Sv) horiz-filtered
    __shared__ float  red[4];

    // normalized 1D Gaussian, sigma=1.5, k=11
    const float W[KW] = {
        0.00102838f, 0.00759874f, 0.03600077f, 0.10936075f, 0.21300553f,
        0.26601172f,
        0.21300553f, 0.10936075f, 0.03600077f, 0.00759874f, 0.00102838f};

    const int tc = blockIdx.x, tr = blockIdx.y, b = blockIdx.z;
    const int tid = threadIdx.x;
    const size_t imgBase = (size_t)b * (IMG * IMG);
    const int gr0 = tr * TH - R;
    const bool colEdge = (tc == 0) || (tc == GX - 1);

    // ========== horizontal pass: 8-px items, single trip (168 <= 256) ======
    if (tid < HB_H * 4) {
        const int rr = tid >> 2;         // staged row 0..41
        const int g  = tid & 3;          // 8-px group in row
        const int gr = gr0 + rr;
        if ((unsigned)gr < (unsigned)IMG) {
            const float4* rx = (const float4*)(x + imgBase + (size_t)gr * IMG);
            const float4* ry = (const float4*)(y + imgBase + (size_t)gr * IMG);
            const int q0 = tc * 8 + 2 * g - 2;  // 6 float4 = f[0..23]; taps f[3..20]
            float fx[24], fy[24];
            if (colEdge) {
#pragma unroll
                for (int i4 = 0; i4 < 6; ++i4) {
                    int q = q0 + i4;
                    int qc = min(max(q, 0), IMG / 4 - 1);
                    float4 vx = rx[qc], vy = ry[qc];
                    float m = (q == qc) ? 1.f : 0.f;
                    fx[4*i4+0]=vx.x*m; fx[4*i4+1]=vx.y*m; fx[4*i4+2]=vx.z*m; fx[4*i4+3]=vx.w*m;
                    fy[4*i4+0]=vy.x*m; fy[4*i4+1]=vy.y*m; fy[4*i4+2]=vy.z*m; fy[4*i4+3]=vy.w*m;
                }
            } else {
#pragma unroll
                for (int i4 = 0; i4 < 6; ++i4) {
                    float4 vx = rx[q0 + i4], vy = ry[q0 + i4];
                    fx[4*i4+0]=vx.x; fx[4*i4+1]=vx.y; fx[4*i4+2]=vx.z; fx[4*i4+3]=vx.w;
                    fy[4*i4+0]=vy.x; fy[4*i4+1]=vy.y; fy[4*i4+2]=vy.z; fy[4*i4+3]=vy.w;
                }
            }
            // j-outer / k-inner, u/v basis, all-pk accumulation
            v2f m[8], s[8];
#pragma unroll
            for (int k = 0; k < 8; ++k) { m[k] = (v2f)(0.f); s[k] = (v2f)(0.f); }
#pragma unroll
            for (int j = 0; j < 18; ++j) {        // input f[3+j]
                const float a = fx[3 + j], c = fy[3 + j];
                const v2f p  = { a + c, a - c };  // (u, v)
                const v2f pp = p * p;             // (u2, v2) pk_mul
#pragma unroll
                for (int k = 0; k < 8; ++k) {
                    const int t = j - k;
                    if (t >= 0 && t < KW) {       // constant-folds
                        const float wt = W[t];
                        m[k] += wt * p;           // pk_fma
                        s[k] += wt * pp;          // pk_fma
                    }
                }
            }
#pragma unroll
            for (int k = 0; k < 8; ++k) {
                const int pos = g + 4 * k;        // permuted column slot
                hb4[rr][pos] = make_float4(m[k].x, m[k].y, s[k].x, s[k].y);
            }
        } else {
            const float4 z = make_float4(0.f, 0.f, 0.f, 0.f);
#pragma unroll
            for (int k = 0; k < 8; ++k) hb4[rr][g + 4 * k] = z;
        }
    }
    __syncthreads();

    // ========== vertical pass + SSIM epilogue: 4 rows/thread ==========
    const int tx  = tid & 31;
    const int ty  = tid >> 5;
    const int r0  = ty * 4;
    const int pos = (tx >> 3) + ((tx & 7) << 2); // same permutation as writer

    v2f vm[4], vs[4];
#pragma unroll
    for (int k = 0; k < 4; ++k) { vm[k] = (v2f)(0.f); vs[k] = (v2f)(0.f); }

#pragma unroll
    for (int t = 0; t < 14; ++t) {       // staged rows r0 .. r0+13
        const float4 h = hb4[r0 + t][pos];
        const v2f a = { h.x, h.y };      // (mu_u, mu_v)
        const v2f d = { h.z, h.w };      // (Su, Sv)
#pragma unroll
        for (int k = 0; k < 4; ++k) {
            const int u = t - k;
            if (u >= 0 && u < KW) {
                const float wt = W[u];
                vm[k] += wt * a;         // pk_fma
                vs[k] += wt * d;         // pk_fma
            }
        }
    }

    float lsum = 0.f;
#pragma unroll
    for (int k = 0; k < 4; ++k) {
        const v2f sq = vm[k] * vm[k];    // (A, B) = (mu_u^2, mu_v^2)
        const float A = sq.x, B = sq.y;
        const float Su = vs[k].x, Sv = vs[k].y;
        const float AmB = A - B, ApB = A + B;
        const float t1 = 0.5f * AmB + C1f;                 // 2 mux muy + C1
        const float t2 = 0.5f * ((Su - Sv) - AmB) + C2f;   // 2 sxy + C2
        const float t3 = 0.5f * ApB + C1f;                 // mux^2+muy^2 + C1
        const float t4 = 0.5f * ((Su + Sv) - ApB) + C2f;   // sx+sy + C2
        float ssim = (t1 * t2) / (t3 * t4 + 1e-12f);
        ssim = fminf(fmaxf(ssim, -1.f + 1e-6f), 1.f - 1e-6f);
        lsum += ssim;
    }

    // ========== block reduction + fence-free packed-atomic finalize ==========
#pragma unroll
    for (int off = 32; off > 0; off >>= 1)
        lsum += __shfl_down(lsum, off, 64);
    if ((tid & 63) == 0) red[tid >> 6] = lsum;
    __syncthreads();
    if (tid == 0) {
        const float s = red[0] + red[1] + red[2] + red[3];
        const int fid  = ((b * GY) + tr) * GX + tc;
        const int slot = fid & (NSLOTS - 1);

        const long long v = (long long)llrintf(s * SCALEF);   // |v| <= 2^34
        const unsigned long long sAdd =
            (1ull << SSHIFT) | (unsigned long long)(v + BIAS1);
        unsigned long long old = atomicAdd(&ws[16 * slot], sAdd);
        if ((old >> SSHIFT) == (unsigned long long)(PERSLOT - 1)) {
            const long long slotSum =
                (long long)((old & ((1ull << SSHIFT) - 1)) +
                            (unsigned long long)(v + BIAS1))
                - (long long)PERSLOT * BIAS1;
            const unsigned long long gAdd =
                (1ull << GSHIFT) | (unsigned long long)(slotSum + BIAS2);
            unsigned long long gold = atomicAdd(&ws[16 * NSLOTS], gAdd);
            if ((gold >> GSHIFT) == (unsigned long long)(NSLOTS - 1)) {
                const long long total =
                    (long long)((gold & ((1ull << GSHIFT) - 1)) +
                                (unsigned long long)(slotSum + BIAS2))
                    - (long long)NSLOTS * BIAS2;
                const double mean =
                    (double)total / ((double)SCALEF * (double)NBLOCKS * (double)(TW * TH));
                out[0] = (float)(1.0 - mean);
            }
        }
    }
}

extern "C" void kernel_launch(void* const* d_in, const int* in_sizes, int n_in,
                              void* d_out, int out_size, void* d_ws, size_t ws_size,
                              hipStream_t stream) {
    const float* x = (const float*)d_in[0];
    const float* y = (const float*)d_in[1];
    float* out = (float*)d_out;
    unsigned long long* ws = (unsigned long long*)d_ws;

    hipMemsetAsync(d_ws, 0, (NSLOTS + 1) * 128, stream);
    dim3 grid(GX, GY, NBATCH);
    ssim_fused_kernel<<<grid, 256, 0, stream>>>(x, y, out, ws);
}